// Round 12
// baseline (437.327 us; speedup 1.0000x reference)
//
#include <hip/hip_runtime.h>
#include <hip/hip_cooperative_groups.h>
#include <math.h>

namespace cg = cooperative_groups;

#define B_ 8
#define S_ 1024
#define INNER_ 288
#define NHM_ 4
#define DHM_ 72
#define H_ 32
#define W_ 32

typedef unsigned short ushort_t;
typedef unsigned int uint_t;
typedef __bf16 bf16x8 __attribute__((ext_vector_type(8)));
typedef float f32x4 __attribute__((ext_vector_type(4)));

__device__ __forceinline__ ushort_t f2bf(float f) {
  union { float f; unsigned u; } v; v.f = f;
  unsigned r = v.u + 0x7FFF + ((v.u >> 16) & 1);
  return (ushort_t)(r >> 16);
}
__device__ __forceinline__ float bf2f(ushort_t u) {
  union { unsigned u; float f; } v; v.u = ((unsigned)u) << 16;
  return v.f;
}
__device__ __forceinline__ void gl16(const void* g, void* l) {
  __builtin_amdgcn_global_load_lds(
      (const __attribute__((address_space(1))) void*)g,
      (__attribute__((address_space(3))) void*)l, 16, 0, 0);
}

// ---------------- prep: all fp32->swizzled-bf16 cvts + zero pads ------------
__global__ __launch_bounds__(256) void prep_kernel(
    const float* __restrict__ x, const float* __restrict__ wupf,
    const float* __restrict__ wdnf,
    ushort_t* __restrict__ xbf, ushort_t* __restrict__ wup, ushort_t* __restrict__ wdn,
    ushort_t* __restrict__ hsb, ushort_t* __restrict__ qg, ushort_t* __restrict__ kg) {
  int s4 = blockIdx.x * 256 + threadIdx.x;
  const ushort4 z4 = {0, 0, 0, 0};
  if (s4 < 393216) {           // xbf: 8192x192, K=192
    const int m = s4 / 48, k4 = (s4 % 48) * 4;
    const float4 v = *(const float4*)&x[(size_t)m * 192 + k4];
    ushort4 w = {f2bf(v.x), f2bf(v.y), f2bf(v.z), f2bf(v.w)};
    *(ushort4*)&xbf[(size_t)m * 192 + (k4 & ~63) + ((k4 & 63) ^ ((m & 7) << 3))] = w;
    return;
  }
  s4 -= 393216;
  if (s4 < 27648) {            // wup: 576x192
    const int m = s4 / 48, k4 = (s4 % 48) * 4;
    const float4 v = *(const float4*)&wupf[(size_t)m * 192 + k4];
    ushort4 w = {f2bf(v.x), f2bf(v.y), f2bf(v.z), f2bf(v.w)};
    *(ushort4*)&wup[(size_t)m * 192 + (k4 & ~63) + ((k4 & 63) ^ ((m & 7) << 3))] = w;
    return;
  }
  s4 -= 27648;
  if (s4 < 15360) {            // wdn: 192x320, K=288
    const int m = s4 / 80, k4 = (s4 % 80) * 4;
    ushort4 w = z4;
    if (k4 < 288) {
      const float4 v = *(const float4*)&wdnf[(size_t)m * 288 + k4];
      w = (ushort4){f2bf(v.x), f2bf(v.y), f2bf(v.z), f2bf(v.w)};
    }
    *(ushort4*)&wdn[(size_t)m * 320 + (k4 & ~63) + ((k4 & 63) ^ ((m & 7) << 3))] = w;
    return;
  }
  s4 -= 15360;
  if (s4 < 131072) {           // hsb cols [256,320) zero
    const int p = s4 >> 4, j = s4 & 15;
    *(ushort4*)&hsb[(size_t)p * 320 + 256 + j * 4] = z4;
    return;
  }
  s4 -= 131072;
  if (s4 < 524288) {           // qg cols [64,128) zero
    const int r = s4 >> 4, j = s4 & 15;
    *(ushort4*)&qg[(size_t)r * 128 + 64 + j * 4] = z4;
    return;
  }
  s4 -= 524288;
  {                            // kg cols [64,128) zero
    const int r = s4 >> 4, j = s4 & 15;
    *(ushort4*)&kg[(size_t)r * 128 + 64 + j * 4] = z4;
  }
}

// ---------------- bf16 MFMA GEMM: C[M,N] = A[M,K] @ B[N,K]^T ----------------
template<int KT>
__global__ __launch_bounds__(256) void gemm_bf16(
    const ushort_t* __restrict__ A, const ushort_t* __restrict__ Bw,
    float* __restrict__ C, int N) {
  __shared__ __align__(16) ushort_t As[2][128 * 64];
  __shared__ __align__(16) ushort_t Bs[2][64 * 64];
  const int tid = threadIdx.x, lane = tid & 63, wv = tid >> 6;
  const int wm = wv >> 1, wn = wv & 1;
  const int cl = lane & 15, rowb = lane >> 4;
  const int m0 = blockIdx.y * 128, n0 = blockIdx.x * 64;
  const char* Ab = (const char*)A;
  const char* Bb = (const char*)Bw;

  auto stage = [&](int buf, int kt) {
    for (int u = wv; u < 24; u += 4) {
      if (u < 16) {
        const int o = u * 1024 + lane * 16;
        const int r = o >> 7, c = o & 127;
        gl16(Ab + ((size_t)(m0 + r) * KT + kt) * 128 + c, (char*)As[buf] + u * 1024);
      } else {
        const int o = (u - 16) * 1024 + lane * 16;
        const int r = o >> 7, c = o & 127;
        gl16(Bb + ((size_t)(n0 + r) * KT + kt) * 128 + c, (char*)Bs[buf] + (u - 16) * 1024);
      }
    }
  };

  f32x4 acc[4][2];
#pragma unroll
  for (int mi = 0; mi < 4; ++mi)
#pragma unroll
    for (int nj = 0; nj < 2; ++nj) acc[mi][nj] = (f32x4){0.f, 0.f, 0.f, 0.f};

  stage(0, 0);
  __syncthreads();
  for (int kt = 0; kt < KT; ++kt) {
    const int cur = kt & 1;
    if (kt + 1 < KT) stage(cur ^ 1, kt + 1);
#pragma unroll
    for (int ks = 0; ks < 2; ++ks) {
      bf16x8 af[4], bfr[2];
#pragma unroll
      for (int mi = 0; mi < 4; ++mi) {
        const int row = wm * 64 + mi * 16 + cl;
        af[mi] = *(const bf16x8*)((const char*)As[cur] + row * 128 +
                                  ((2 * (ks * 32 + rowb * 8)) ^ ((row & 7) << 4)));
      }
#pragma unroll
      for (int nj = 0; nj < 2; ++nj) {
        const int row = wn * 32 + nj * 16 + cl;
        bfr[nj] = *(const bf16x8*)((const char*)Bs[cur] + row * 128 +
                                   ((2 * (ks * 32 + rowb * 8)) ^ ((row & 7) << 4)));
      }
#pragma unroll
      for (int mi = 0; mi < 4; ++mi)
#pragma unroll
        for (int nj = 0; nj < 2; ++nj)
          acc[mi][nj] = __builtin_amdgcn_mfma_f32_16x16x32_bf16(af[mi], bfr[nj], acc[mi][nj], 0, 0, 0);
    }
    __syncthreads();
  }
#pragma unroll
  for (int mi = 0; mi < 4; ++mi)
#pragma unroll
    for (int i = 0; i < 4; ++i) {
      const size_t m = m0 + wm * 64 + mi * 16 + rowb * 4 + i;
#pragma unroll
      for (int nj = 0; nj < 2; ++nj)
        C[m * N + n0 + wn * 32 + nj * 16 + cl] = acc[mi][nj][i];
    }
}

// ---------------- fused middle chain: conv+head | vtrans | gates | scan |
// ---------------- mlstm+LN  (cooperative, grid 512x256, LDS 67072B) --------
__global__ __launch_bounds__(256, 2) void fused_mid(
    const float* __restrict__ y, const float* __restrict__ cw,
    const float* __restrict__ qw, const float* __restrict__ kw, const float* __restrict__ vw,
    const float* __restrict__ igw, const float* __restrict__ igbias,
    const float* __restrict__ fgw, const float* __restrict__ fgbias,
    float* __restrict__ xa, ushort_t* __restrict__ qg, ushort_t* __restrict__ kg,
    ushort_t* __restrict__ vg, ushort_t* __restrict__ vtg,
    float* __restrict__ igb_, float* __restrict__ fgb_, float* __restrict__ lfcb,
    float* __restrict__ gbuf, float* __restrict__ Mbuf,
    const float* __restrict__ normw, const float* __restrict__ skipw,
    ushort_t* __restrict__ hsb) {
  __shared__ __align__(16) unsigned char smem[67072];
  cg::grid_group grid = cg::this_grid();
  const int bi = blockIdx.x, tid = threadIdx.x;
  const int lane = tid & 63, wv = tid >> 6;

  // ======== Phase A: depthwise conv3x3 + SiLU + headwise q/k/v ========
  for (int idx = bi * 256 + tid; idx < 8192 * 72; idx += 512 * 256) {
    const int hq = idx % 72;
    const int p = idx / 72;
    const int c = hq * 4;
    const int xx = p & 31, yy = (p >> 5) & 31, b = p >> 10, s = p & 1023;
    float4 acc = {0.f, 0.f, 0.f, 0.f};
    float4 xmv;
#pragma unroll
    for (int ky = 0; ky < 3; ++ky) {
      const int iy = yy + ky - 1;
      if (iy < 0 || iy >= H_) continue;
#pragma unroll
      for (int kx = 0; kx < 3; ++kx) {
        const int ix = xx + kx - 1;
        if (ix < 0 || ix >= W_) continue;
        const float4 v = *(const float4*)&y[((size_t)((b << 10) + (iy << 5) + ix)) * 576 + c];
        if (ky == 1 && kx == 1) xmv = v;
        const float4 w = *(const float4*)&cw[(ky * 3 + kx) * INNER_ + c];
        acc.x += v.x * w.x; acc.y += v.y * w.y; acc.z += v.z * w.z; acc.w += v.w * w.w;
      }
    }
    float4 xa4;
    xa4.x = acc.x / (1.f + __expf(-acc.x));
    xa4.y = acc.y / (1.f + __expf(-acc.y));
    xa4.z = acc.z / (1.f + __expf(-acc.z));
    xa4.w = acc.w / (1.f + __expf(-acc.w));
    *(float4*)&xa[(size_t)p * INNER_ + c] = xa4;
    float q[4], k2[4], v[4];
#pragma unroll
    for (int o = 0; o < 4; ++o) {
      const float4 wq = *(const float4*)&qw[hq * 16 + o * 4];
      const float4 wk = *(const float4*)&kw[hq * 16 + o * 4];
      const float4 wv4 = *(const float4*)&vw[hq * 16 + o * 4];
      q[o]  = wq.x * xa4.x + wq.y * xa4.y + wq.z * xa4.z + wq.w * xa4.w;
      k2[o] = wk.x * xa4.x + wk.y * xa4.y + wk.z * xa4.z + wk.w * xa4.w;
      v[o]  = wv4.x * xmv.x + wv4.y * xmv.y + wv4.z * xmv.z + wv4.w * xmv.w;
    }
    const int n = hq / 18, g = hq % 18;
    const int r = (b * 4 + n) * 1024 + s;
    const int swz = (s & 7) << 3;
    ushort4 uq = {f2bf(q[0]), f2bf(q[1]), f2bf(q[2]), f2bf(q[3])};
    ushort4 uk = {f2bf(k2[0]), f2bf(k2[1]), f2bf(k2[2]), f2bf(k2[3])};
    ushort4 uv = {f2bf(v[0]), f2bf(v[1]), f2bf(v[2]), f2bf(v[3])};
    *(ushort4*)&qg[(size_t)r * 128 + ((g * 4) ^ swz)] = uq;
    *(ushort4*)&kg[(size_t)r * 128 + ((g * 4) ^ swz)] = uk;
    *(ushort4*)&vg[(size_t)r * 72 + g * 4] = uv;
  }
  grid.sync();

  // ======== Phase B: V transpose -> per-tile swizzled [bn][tt][80x64] ======
  {
    ushort_t (*T)[82] = (ushort_t (*)[82])smem;
    const int bn = bi >> 4, tt = bi & 15;
    const int s0 = tt << 6;
    const uint_t* v32 = (const uint_t*)vg;
    for (int i = tid; i < 64 * 36; i += 256) {
      const int rr = i / 36, c2 = i % 36;
      *(uint_t*)&T[rr][c2 * 2] = v32[((size_t)(bn * 1024 + s0 + rr)) * 36 + c2];
    }
    __syncthreads();
    char* outb = (char*)(vtg + ((size_t)(bn * 16 + tt)) * 5120);
    for (int i = tid; i < 80 * 32; i += 256) {
      const int d = i >> 5, m = i & 31;
      uint_t val;
      if (d < 72) val = (uint_t)T[2 * m][d] | ((uint_t)T[2 * m + 1][d] << 16);
      else val = (d == 72) ? 0x3F803F80u : 0u;
      *(uint_t*)(outb + d * 128 + ((m * 4) ^ ((d & 7) << 4))) = val;
    }
  }
  grid.sync();

  // ======== Phase C: gates (4 positions per wave) ========
  for (int kk = 0; kk < 4; ++kk) {
    const int gw = bi * 4 + wv + kk * 2048;   // b*S+s
    const int b = gw >> 10, s = gw & 1023;
    float iacc[4] = {}, facc[4] = {};
    for (int j = lane; j < 864; j += 64) {
      const int part = j / INNER_;
      const int c = j - part * INNER_;
      const int n = c / DHM_, d = c % DHM_;
      const size_t row = (size_t)(b * 4 + n) * 1024 + s;
      ushort_t u;
      if (part == 2)      u = vg[row * 72 + d];
      else {
        const size_t si = row * 128 + (d ^ ((row & 7) << 3));
        u = (part == 0) ? qg[si] : kg[si];
      }
      const float gv = bf2f(u);
#pragma unroll
      for (int nn = 0; nn < 4; ++nn) {
        iacc[nn] += gv * igw[nn * 864 + j];
        facc[nn] += gv * fgw[nn * 864 + j];
      }
    }
#pragma unroll
    for (int off = 32; off >= 1; off >>= 1) {
#pragma unroll
      for (int nn = 0; nn < 4; ++nn) {
        iacc[nn] += __shfl_xor(iacc[nn], off);
        facc[nn] += __shfl_xor(facc[nn], off);
      }
    }
    if (lane == 0) {
#pragma unroll
      for (int nn = 0; nn < 4; ++nn) {
        igb_[((size_t)b * NHM_ + nn) * S_ + s] = iacc[nn] + igbias[nn];
        fgb_[((size_t)b * NHM_ + nn) * S_ + s] = facc[nn] + fgbias[nn];
      }
    }
  }
  grid.sync();

  // ======== Phase D: per-(b,n) scans (blocks 0..31) ========
  if (bi < 32) {
    float* sd = (float*)smem;
    const int bn = bi;
    const float* fgp = &fgb_[(size_t)bn * S_];
    const float* igp = &igb_[(size_t)bn * S_];
    float lf[4];
#pragma unroll
    for (int i = 0; i < 4; ++i) {
      const float f = fgp[tid * 4 + i];
      lf[i] = (f >= 0.f) ? -log1pf(expf(-f)) : (f - log1pf(expf(f)));
    }
    float p[4];
    p[0] = lf[0]; p[1] = p[0] + lf[1]; p[2] = p[1] + lf[2]; p[3] = p[2] + lf[3];
    sd[tid] = p[3];
    __syncthreads();
    for (int off = 1; off < 256; off <<= 1) {
      const float v = (tid >= off) ? sd[tid - off] : 0.f;
      __syncthreads();
      sd[tid] += v;
      __syncthreads();
    }
    const float excl = sd[tid] - p[3];
    float l[4];
#pragma unroll
    for (int i = 0; i < 4; ++i) {
      l[i] = excl + p[i];
      lfcb[(size_t)bn * S_ + tid * 4 + i] = l[i];
    }
    float gv[4], pm[4];
#pragma unroll
    for (int i = 0; i < 4; ++i) gv[i] = igp[tid * 4 + i] - l[i];
    pm[0] = gv[0];
#pragma unroll
    for (int i = 1; i < 4; ++i) pm[i] = fmaxf(pm[i - 1], gv[i]);
    __syncthreads();
    sd[tid] = pm[3];
    __syncthreads();
    for (int off = 1; off < 256; off <<= 1) {
      const float v = (tid >= off) ? sd[tid - off] : -INFINITY;
      __syncthreads();
      sd[tid] = fmaxf(sd[tid], v);
      __syncthreads();
    }
    const float exclm = (tid > 0) ? sd[tid - 1] : -INFINITY;
#pragma unroll
    for (int i = 0; i < 4; ++i) {
      gbuf[(size_t)bn * S_ + tid * 4 + i] = gv[i];
      Mbuf[(size_t)bn * S_ + tid * 4 + i] = fmaxf(exclm, pm[i]);
    }
  }
  grid.sync();

  // ======== Phase E: mLSTM core + fused LN/skip/silu -> hsb ========
  {
    ushort_t* Ks0 = (ushort_t*)smem;                 // [2][64*128]
    ushort_t* Vt0 = (ushort_t*)(smem + 32768);       // [2][80*64]
    ushort_t* Ps  = (ushort_t*)(smem + 53248);       // [64*72]
    float* gs     = (float*)(smem + 62464);          // [1024]
    float* Ms_s   = (float*)(smem + 66560);          // [64]
    float* en_s   = (float*)(smem + 66816);          // [64]
    const int bn = bi & 31;
    const int j = (bi >> 5) & 7;
    const int st = (bi >> 8) ? (15 - j) : j;
    const int s0 = st << 6;
    const int cl = lane & 15, rowb = lane >> 4;
    const char* kb = (const char*)(kg + (size_t)bn * 1024 * 128);
    const char* vtb = (const char*)(vtg + (size_t)bn * 16 * 5120);

    auto stage = [&](int buf, int tt) {
      const char* ks = kb + (size_t)tt * (64 * 256);
      const char* vs = vtb + (size_t)tt * 10240;
      for (int u = wv; u < 26; u += 4) {
        if (u < 16) gl16(ks + u * 1024 + lane * 16, (char*)Ks0 + buf * 16384 + u * 1024);
        else        gl16(vs + (u - 16) * 1024 + lane * 16, (char*)Vt0 + buf * 10240 + (u - 16) * 1024);
      }
    };

    stage(0, 0);
    *(float4*)&gs[tid * 4] = *(const float4*)&gbuf[(size_t)bn * S_ + tid * 4];
    if (tid < 64) {
      const float m = Mbuf[(size_t)bn * S_ + s0 + tid];
      Ms_s[tid] = m;
      en_s[tid] = __expf(-(lfcb[(size_t)bn * S_ + s0 + tid] + m));
    }
    const int qrow = bn * 1024 + s0 + 16 * wv + cl;
    const ushort_t* qp = qg + (size_t)qrow * 128;
    const int qx = (qrow & 7) << 3;
    bf16x8 qf[3];
#pragma unroll
    for (int kk = 0; kk < 3; ++kk) qf[kk] = *(const bf16x8*)&qp[(kk * 32 + rowb * 8) ^ qx];

    f32x4 accv[5];
#pragma unroll
    for (int n0 = 0; n0 < 5; ++n0) accv[n0] = (f32x4){0.f, 0.f, 0.f, 0.f};
    const float rsc = 0.11785113019775793f;   // 1/sqrt(72)
    const int srl0 = 16 * wv + 4 * rowb;
    __syncthreads();

    for (int tt = 0; tt < st; ++tt) {
      const int cur = tt & 1;
      stage(cur ^ 1, tt + 1);
      const int t0 = tt << 6;
      f32x4 qk[4];
#pragma unroll
      for (int n0 = 0; n0 < 4; ++n0) qk[n0] = (f32x4){0.f, 0.f, 0.f, 0.f};
#pragma unroll
      for (int kk = 0; kk < 3; ++kk) {
#pragma unroll
        for (int n0 = 0; n0 < 4; ++n0) {
          const int rl = n0 * 16 + cl;
          const bf16x8 b = *(const bf16x8*)((const char*)Ks0 + cur * 16384 + rl * 256 +
                                            ((2 * (kk * 32 + rowb * 8)) ^ ((rl & 7) << 4)));
          qk[n0] = __builtin_amdgcn_mfma_f32_16x16x32_bf16(qf[kk], b, qk[n0], 0, 0, 0);
        }
      }
#pragma unroll
      for (int n0 = 0; n0 < 4; ++n0) {
        const float gtv = gs[t0 + n0 * 16 + cl];
#pragma unroll
        for (int i = 0; i < 4; ++i) {
          const float w = qk[n0][i] * rsc * __expf(gtv - Ms_s[srl0 + i]);
          Ps[(srl0 + i) * 72 + n0 * 16 + cl] = f2bf(w);
        }
      }
#pragma unroll
      for (int k0 = 0; k0 < 64; k0 += 32) {
        const bf16x8 a = *(const bf16x8*)&Ps[(16 * wv + cl) * 72 + k0 + rowb * 8];
#pragma unroll
        for (int n0 = 0; n0 < 5; ++n0) {
          const int d = n0 * 16 + cl;
          const bf16x8 b = *(const bf16x8*)((const char*)Vt0 + cur * 10240 + d * 128 +
                                            ((2 * (k0 + rowb * 8)) ^ ((d & 7) << 4)));
          accv[n0] = __builtin_amdgcn_mfma_f32_16x16x32_bf16(a, b, accv[n0], 0, 0, 0);
        }
      }
      __syncthreads();
    }
    {   // diagonal tile (causal mask)
      const int cur = st & 1;
      f32x4 qk[4];
#pragma unroll
      for (int n0 = 0; n0 < 4; ++n0) qk[n0] = (f32x4){0.f, 0.f, 0.f, 0.f};
#pragma unroll
      for (int kk = 0; kk < 3; ++kk) {
#pragma unroll
        for (int n0 = 0; n0 < 4; ++n0) {
          const int rl = n0 * 16 + cl;
          const bf16x8 b = *(const bf16x8*)((const char*)Ks0 + cur * 16384 + rl * 256 +
                                            ((2 * (kk * 32 + rowb * 8)) ^ ((rl & 7) << 4)));
          qk[n0] = __builtin_amdgcn_mfma_f32_16x16x32_bf16(qf[kk], b, qk[n0], 0, 0, 0);
        }
      }
#pragma unroll
      for (int n0 = 0; n0 < 4; ++n0) {
        const int tc = n0 * 16 + cl;
        const float gtv = gs[s0 + tc];
#pragma unroll
        for (int i = 0; i < 4; ++i) {
          const int srl = srl0 + i;
          const float w = (tc <= srl) ? qk[n0][i] * rsc * __expf(gtv - Ms_s[srl]) : 0.f;
          Ps[srl * 72 + n0 * 16 + cl] = f2bf(w);
        }
      }
#pragma unroll
      for (int k0 = 0; k0 < 64; k0 += 32) {
        const bf16x8 a = *(const bf16x8*)&Ps[(16 * wv + cl) * 72 + k0 + rowb * 8];
#pragma unroll
        for (int n0 = 0; n0 < 5; ++n0) {
          const int d = n0 * 16 + cl;
          const bf16x8 b = *(const bf16x8*)((const char*)Vt0 + cur * 10240 + d * 128 +
                                            ((2 * (k0 + rowb * 8)) ^ ((d & 7) << 4)));
          accv[n0] = __builtin_amdgcn_mfma_f32_16x16x32_bf16(a, b, accv[n0], 0, 0, 0);
        }
      }
    }
    // epilogue: normalizer -> LN -> +skip*xa -> *silu(z) -> hsb
    float inv[4];
#pragma unroll
    for (int i = 0; i < 4; ++i) {
      const float rs = __shfl(accv[4][i], (lane & 48) + 8, 64);
      inv[i] = 1.f / (fmaxf(fabsf(rs), en_s[srl0 + i]) + 1e-6f);
    }
    const int b = bn >> 2, n = bn & 3;
    float nw[5], sw[5];
#pragma unroll
    for (int n0 = 0; n0 < 5; ++n0) {
      const int d = n0 * 16 + cl;
      nw[n0] = (d < 72) ? normw[n * 72 + d] : 0.f;
      sw[n0] = (d < 72) ? skipw[n * 72 + d] : 0.f;
    }
#pragma unroll
    for (int i = 0; i < 4; ++i) {
      const int srl = srl0 + i;
      const int p = (b << 10) + s0 + srl;
      float hv[5];
#pragma unroll
      for (int n0 = 0; n0 < 5; ++n0) hv[n0] = accv[n0][i] * inv[i];
      float hsum = hv[0] + hv[1] + hv[2] + hv[3] + ((cl < 8) ? hv[4] : 0.f);
#pragma unroll
      for (int m = 1; m < 16; m <<= 1) hsum += __shfl_xor(hsum, m);
      const float mean = hsum * (1.f / 72.f);
      float dsq = 0.f;
#pragma unroll
      for (int n0 = 0; n0 < 5; ++n0) {
        const int d = n0 * 16 + cl;
        const float dd = hv[n0] - mean;
        if (d < 72) dsq += dd * dd;
      }
#pragma unroll
      for (int m = 1; m < 16; m <<= 1) dsq += __shfl_xor(dsq, m);
      const float rstd = rsqrtf(dsq * (1.f / 72.f) + 1e-5f);
      const int pswz = (p & 7) << 3;
#pragma unroll
      for (int n0 = 0; n0 < 5; ++n0) {
        const int d = n0 * 16 + cl;
        if (d < 72) {
          const int c = n * 72 + d;
          const float hn = (hv[n0] - mean) * rstd * nw[n0];
          const float xav = xa[(size_t)p * INNER_ + c];
          const float z = y[(size_t)p * 576 + 288 + c];
          const float sz = z / (1.f + __expf(-z));
          hsb[(size_t)p * 320 + (c & ~63) + ((c & 63) ^ pswz)] = f2bf((hn + sw[n0] * xav) * sz);
        }
      }
    }
  }
}

extern "C" void kernel_launch(void* const* d_in, const int* in_sizes, int n_in,
                              void* d_out, int out_size, void* d_ws, size_t ws_size,
                              hipStream_t stream) {
  const float* x           = (const float*)d_in[0];
  const float* proj_up_w   = (const float*)d_in[1];
  const float* q_w         = (const float*)d_in[2];
  const float* k_w         = (const float*)d_in[3];
  const float* v_w         = (const float*)d_in[4];
  const float* conv_w      = (const float*)d_in[5];
  const float* ig_w        = (const float*)d_in[6];
  const float* ig_b        = (const float*)d_in[7];
  const float* fg_w        = (const float*)d_in[8];
  const float* fg_b        = (const float*)d_in[9];
  const float* norm_w      = (const float*)d_in[10];
  const float* skipw       = (const float*)d_in[11];
  const float* proj_down_w = (const float*)d_in[12];
  float* out = (float*)d_out;

  float* ws = (float*)d_ws;
  float* y      = ws;                            // 8192*576
  float* xa     = y      + (size_t)8192 * 576;   // 8192*288
  float* igb_   = xa     + (size_t)8192 * 288;   // 32768
  float* fgb_   = igb_   + 32768;
  float* lfcb   = fgb_   + 32768;
  float* gbuf   = lfcb   + 32768;
  float* Mbuf   = gbuf   + 32768;
  ushort_t* qg  = (ushort_t*)(Mbuf + 32768);                 // 32*1024*128
  ushort_t* kg  = qg  + (size_t)32 * 1024 * 128;
  ushort_t* vg  = kg  + (size_t)32 * 1024 * 128;             // 32*1024*72
  ushort_t* vtg = vg  + (size_t)32 * 1024 * 72;              // 32*16*5120
  ushort_t* xbf = vtg + (size_t)32 * 16 * 5120;              // 8192*192
  ushort_t* wup = xbf + (size_t)8192 * 192;                  // 576*192
  ushort_t* wdn = wup + (size_t)576 * 192;                   // 192*320
  ushort_t* hsb = wdn + (size_t)192 * 320;                   // 8192*320

  // 1. prep: cvts + zero-pads
  prep_kernel<<<6312, 256, 0, stream>>>(x, proj_up_w, proj_down_w,
                                        xbf, wup, wdn, hsb, qg, kg);
  // 2. proj_up: y = x @ proj_up_w^T (bf16 MFMA)
  gemm_bf16<3><<<dim3(9, 64), 256, 0, stream>>>(xbf, wup, y, 576);
  // 3. fused middle chain (cooperative: conv+head | vtrans | gates | scan | mlstm+LN)
  {
    const float* y_ = y;
    void* args[] = {
      (void*)&y_, (void*)&conv_w, (void*)&q_w, (void*)&k_w, (void*)&v_w,
      (void*)&ig_w, (void*)&ig_b, (void*)&fg_w, (void*)&fg_b,
      (void*)&xa, (void*)&qg, (void*)&kg, (void*)&vg, (void*)&vtg,
      (void*)&igb_, (void*)&fgb_, (void*)&lfcb, (void*)&gbuf, (void*)&Mbuf,
      (void*)&norm_w, (void*)&skipw, (void*)&hsb};
    hipLaunchCooperativeKernel((void*)fused_mid, dim3(512), dim3(256), args, 0, stream);
  }
  // 4. proj_down (bf16 MFMA)
  gemm_bf16<5><<<dim3(3, 64), 256, 0, stream>>>(hsb, wdn, out, 192);
}